// Round 4
// baseline (137.373 us; speedup 1.0000x reference)
//
#include <hip/hip_runtime.h>
#include <stdint.h>

// pooled[b,o] = x[b,:] . Wp[o,:] + biasp[o] + 0.25*(y[b,n0]+y[b,n0+1]+y[b,n0+64]+y[b,n0+65])
//   o = p*32+q, n0 = 128p+2q; Wp = 2x2-pooled W rows. out = pooled / mean(pooled).
// Single-pass GEMM with manual grid barrier: epilogue keeps pooled vals in
// VGPRs across the barrier, every block redundantly reduces the 512 partials
// (identical fp order -> identical deterministic inv), scales regs, writes out
// once. Barrier counter is reset by k_prep on every launch (graph-replay safe).
// Co-residency: 512 blocks = 2/CU (64KB LDS) x 256 CU exactly.

#define KDIM 1024
#define NP   1024
#define BM 128
#define BN 128
#define BK 64
#define NBLK 512

typedef __bf16 bf16x8 __attribute__((ext_vector_type(8)));
typedef float f32x4 __attribute__((ext_vector_type(4)));

__device__ __forceinline__ unsigned f2bf(float f) {
  union { float f; unsigned u; } v; v.f = f;
  unsigned r = v.u + 0x7fffu + ((v.u >> 16) & 1u);  // RNE
  return r >> 16;
}

__device__ __forceinline__ void gload_lds16(const void* g, void* l) {
  __builtin_amdgcn_global_load_lds(
      (const __attribute__((address_space(1))) void*)g,
      (__attribute__((address_space(3))) void*)l, 16, 0, 0);
}

// ---- kernel 1 (merged prep): x fp32->bf16 (blocks 0..4095), pool W+bias, reset barrier ----
__global__ void k_prep(const float* __restrict__ x, const float* __restrict__ W,
                       const float* __restrict__ bias,
                       unsigned short* __restrict__ xb, unsigned short* __restrict__ wp,
                       float* __restrict__ biasp, unsigned* __restrict__ counter) {
  int b = blockIdx.x;
  int t = threadIdx.x;
  if (b < 4096) {
    int i = b * 256 + t;  // 8 elems per thread
    const float4* x4 = (const float4*)x;
    float4 a = x4[i * 2], c = x4[i * 2 + 1];
    uint4 o;
    o.x = f2bf(a.x) | (f2bf(a.y) << 16);
    o.y = f2bf(a.z) | (f2bf(a.w) << 16);
    o.z = f2bf(c.x) | (f2bf(c.y) << 16);
    o.w = f2bf(c.z) | (f2bf(c.w) << 16);
    ((uint4*)xb)[i] = o;
    if (b == 0 && t == 0)
      __hip_atomic_store(counter, 0u, __ATOMIC_RELAXED, __HIP_MEMORY_SCOPE_AGENT);
  } else {
    int o = b - 4096;  // pooled feature index
    int r0 = ((o >> 5) << 7) + ((o & 31) << 1);
    const float4* W4 = (const float4*)W;
    float4 w0 = W4[(r0) * 256 + t];
    float4 w1 = W4[(r0 + 1) * 256 + t];
    float4 w2 = W4[(r0 + 64) * 256 + t];
    float4 w3 = W4[(r0 + 65) * 256 + t];
    float ax = 0.25f * (w0.x + w1.x + w2.x + w3.x);
    float ay = 0.25f * (w0.y + w1.y + w2.y + w3.y);
    float az = 0.25f * (w0.z + w1.z + w2.z + w3.z);
    float aw = 0.25f * (w0.w + w1.w + w2.w + w3.w);
    uint2 pk;
    pk.x = f2bf(ax) | (f2bf(ay) << 16);
    pk.y = f2bf(az) | (f2bf(aw) << 16);
    ((uint2*)wp)[o * 256 + t] = pk;
    if (t == 0)
      biasp[o] = 0.25f * (bias[r0] + bias[r0 + 1] + bias[r0 + 64] + bias[r0 + 65]);
  }
}

// ---- kernel 2: GEMM + epilogue + manual grid barrier + scale ----
__global__ __launch_bounds__(256) void k_gemm(
    const unsigned short* __restrict__ xb, const unsigned short* __restrict__ wp,
    const float* __restrict__ biasp, const float* __restrict__ y,
    float* __restrict__ out, float* __restrict__ partials,
    unsigned* __restrict__ counter) {
  // layout: buf in {0,1}: As(buf)=smem+buf*32768 (16KB), Bs(buf)=+16384
  __shared__ char smem[65536];

  int bid = blockIdx.x;
  // XCD swizzle: nwg=512 = 8*64, bijective
  int wg = (bid & 7) * 64 + (bid >> 3);
  int bm0 = (wg >> 3) * BM;
  int bn0 = (wg & 7) * BN;

  int tid = threadIdx.x;
  int lane = tid & 63;
  int wid = tid >> 6;
  int wr = wid >> 1, wc = wid & 1;  // wave tile 64x64

  f32x4 acc[4][4];
#pragma unroll
  for (int i = 0; i < 4; i++)
#pragma unroll
    for (int j = 0; j < 4; j++) acc[i][j] = (f32x4)0.0f;

  // staging: wave covers rows [wid*32, +32) over 4 calls of 8 rows each.
  // LDS dest linear; SOURCE column chunk pre-swizzled by (lane&7)^(lane>>3)
  // so the swizzled READ sees correct data (both-sides involution).
  int srow = wid * 32 + (lane >> 3);
  int scol = (((lane & 7) ^ (lane >> 3)) << 3);
  const unsigned short* aSrc = xb + (size_t)(bm0 + srow) * KDIM + scol;
  const unsigned short* bSrc = wp + (size_t)(bn0 + srow) * KDIM + scol;
  int ldsOff = wid * 4096;

  int rbase = (lane & 15) * 128;
  int xorv = (lane & 7) << 4;
  int cb0 = (((lane >> 4) * 16)) ^ xorv;
  int cb1 = ((64 + (lane >> 4) * 16)) ^ xorv;

#define STAGE(buf, ks)                                                         \
  {                                                                            \
    int k0 = (ks) * BK;                                                        \
    char* ab = smem + (buf) * 32768 + ldsOff;                                  \
    char* bb = smem + (buf) * 32768 + 16384 + ldsOff;                          \
    _Pragma("unroll")                                                          \
    for (int i = 0; i < 4; ++i) {                                              \
      gload_lds16(aSrc + (size_t)i * 8 * KDIM + k0, ab + i * 1024);            \
      gload_lds16(bSrc + (size_t)i * 8 * KDIM + k0, bb + i * 1024);            \
    }                                                                          \
  }

  STAGE(0, 0);
  for (int ks = 0; ks < 16; ++ks) {
    int cur = ks & 1;
    if (ks < 15) {
      STAGE(cur ^ 1, ks + 1);
      asm volatile("s_waitcnt vmcnt(8)" ::: "memory");
    } else {
      asm volatile("s_waitcnt vmcnt(0)" ::: "memory");
    }
    __builtin_amdgcn_s_barrier();
    asm volatile("" ::: "memory");
    const char* Ab = smem + cur * 32768;
    const char* Bb = Ab + 16384;
#pragma unroll
    for (int kk = 0; kk < 2; ++kk) {
      int cb = kk ? cb1 : cb0;
      bf16x8 af[4], bfr[4];
#pragma unroll
      for (int mi = 0; mi < 4; ++mi)
        af[mi] = *(const bf16x8*)(Ab + (wr * 64 + mi * 16) * 128 + rbase + cb);
#pragma unroll
      for (int ni = 0; ni < 4; ++ni)
        bfr[ni] = *(const bf16x8*)(Bb + (wc * 64 + ni * 16) * 128 + rbase + cb);
#pragma unroll
      for (int mi = 0; mi < 4; ++mi)
#pragma unroll
        for (int ni = 0; ni < 4; ++ni)
          acc[mi][ni] = __builtin_amdgcn_mfma_f32_16x16x32_bf16(af[mi], bfr[ni], acc[mi][ni], 0, 0, 0);
    }
    asm volatile("" ::: "memory");
    __builtin_amdgcn_s_barrier();
  }

  // epilogue: add pooled bias + pooled y into registers, accumulate block sum
  const float2* y2 = (const float2*)y;
  float tsum = 0.f;
  int r_l = (lane >> 4) * 4;
  int c_l = lane & 15;
#pragma unroll
  for (int mi = 0; mi < 4; ++mi) {
#pragma unroll
    for (int ni = 0; ni < 4; ++ni) {
      int col = bn0 + wc * 64 + ni * 16 + c_l;  // pooled feature o
      float bp = biasp[col];
      int y2base = ((col >> 5) << 6) + (col & 31);
#pragma unroll
      for (int j = 0; j < 4; ++j) {
        int row = bm0 + wr * 64 + mi * 16 + r_l + j;  // batch b
        float2 u = y2[(size_t)row * 2048 + y2base];
        float2 v = y2[(size_t)row * 2048 + y2base + 32];
        float val = acc[mi][ni][j] + bp + 0.25f * (u.x + u.y + v.x + v.y);
        acc[mi][ni][j] = val;
        tsum += val;
      }
    }
  }
#pragma unroll
  for (int off = 32; off > 0; off >>= 1) tsum += __shfl_down(tsum, off);
  float* sm = (float*)smem;
  __syncthreads();
  if (lane == 0) sm[wid] = tsum;
  __syncthreads();

  // ---- manual grid barrier (all 512 blocks co-resident by construction) ----
  if (tid == 0) {
    float p = sm[0] + sm[1] + sm[2] + sm[3];
    __hip_atomic_store(&partials[bid], p, __ATOMIC_RELEASE, __HIP_MEMORY_SCOPE_AGENT);
    __hip_atomic_fetch_add(counter, 1u, __ATOMIC_ACQ_REL, __HIP_MEMORY_SCOPE_AGENT);
    // bounded spin: legit wait is ~100K cycles; bound ~4e9 cycles avoids a
    // hard hang in a pathological case (fails validation instead).
    for (long it = 0; it < (1L << 26); ++it) {
      if (__hip_atomic_load(counter, __ATOMIC_ACQUIRE, __HIP_MEMORY_SCOPE_AGENT) >= NBLK) break;
      __builtin_amdgcn_s_sleep(8);
    }
  }
  __syncthreads();

  // every block redundantly reduces all 512 partials (identical order ->
  // identical deterministic result in every block)
  float pv = __hip_atomic_load(&partials[tid], __ATOMIC_RELAXED, __HIP_MEMORY_SCOPE_AGENT) +
             __hip_atomic_load(&partials[tid + 256], __ATOMIC_RELAXED, __HIP_MEMORY_SCOPE_AGENT);
  __syncthreads();
  sm[tid] = pv;
  __syncthreads();
#pragma unroll
  for (int off = 128; off > 0; off >>= 1) {
    if (tid < off) sm[tid] += sm[tid + off];
    __syncthreads();
  }
  float inv = 8388608.0f / sm[0];  // 1/mean = (B*NP)/total

  // scale registers and write out (single store pass)
#pragma unroll
  for (int mi = 0; mi < 4; ++mi) {
#pragma unroll
    for (int ni = 0; ni < 4; ++ni) {
      int col = bn0 + wc * 64 + ni * 16 + c_l;
#pragma unroll
      for (int j = 0; j < 4; ++j) {
        int row = bm0 + wr * 64 + mi * 16 + r_l + j;
        out[(size_t)row * NP + col] = acc[mi][ni][j] * inv;
      }
    }
  }
}

extern "C" void kernel_launch(void* const* d_in, const int* in_sizes, int n_in,
                              void* d_out, int out_size, void* d_ws, size_t ws_size,
                              hipStream_t stream) {
  (void)in_sizes; (void)n_in; (void)out_size; (void)ws_size;
  const float* x = (const float*)d_in[0];
  const float* y = (const float*)d_in[1];
  const float* W = (const float*)d_in[2];
  const float* bias = (const float*)d_in[3];
  float* out = (float*)d_out;

  char* ws = (char*)d_ws;
  unsigned short* xb = (unsigned short*)(ws);                      // 16 MiB
  unsigned short* wp = (unsigned short*)(ws + 16777216);           // 2 MiB
  float* biasp = (float*)(ws + 16777216 + 2097152);                // 4 KiB
  float* partials = (float*)(ws + 16777216 + 2097152 + 4096);      // 2 KiB
  unsigned* counter = (unsigned*)(ws + 16777216 + 2097152 + 8192); // own line

  hipLaunchKernelGGL(k_prep, dim3(5120), dim3(256), 0, stream, x, W, bias, xb, wp, biasp, counter);
  hipLaunchKernelGGL(k_gemm, dim3(512), dim3(256), 0, stream, xb, wp, biasp, y, out, partials, counter);
}

// Round 5
// 69.994 us; speedup vs baseline: 1.9626x; 1.9626x over previous
//
#include <hip/hip_runtime.h>
#include <stdint.h>

// pooled[b,o] = x[b,:] . Wp[o,:] + biasp[o] + 0.25*(y[b,n0]+y[b,n0+1]+y[b,n0+64]+y[b,n0+65])
//   o = p*32+q, n0 = 128p+2q; Wp = 2x2-pooled W rows. out = pooled / mean(pooled).
// 3 dispatches: prep (x->bf16, pool W/bias) -> gemm (256x128 tiles, dbuf LDS,
// counted vmcnt, XOR swizzle; epilogue adds bias+pooled-y, writes raw out +
// per-block partial sums) -> norm (every block redundantly reduces the 256
// partials -> identical deterministic inv, scales out in place).

#define KDIM 1024
#define NP   1024
#define BM 256
#define BN 128
#define BK 64
#define NBLK 256

typedef __bf16 bf16x8 __attribute__((ext_vector_type(8)));
typedef float f32x4 __attribute__((ext_vector_type(4)));

__device__ __forceinline__ unsigned f2bf(float f) {
  union { float f; unsigned u; } v; v.f = f;
  unsigned r = v.u + 0x7fffu + ((v.u >> 16) & 1u);  // RNE
  return r >> 16;
}

__device__ __forceinline__ void gload_lds16(const void* g, void* l) {
  __builtin_amdgcn_global_load_lds(
      (const __attribute__((address_space(1))) void*)g,
      (__attribute__((address_space(3))) void*)l, 16, 0, 0);
}

// ---- kernel 1 (merged prep): x fp32->bf16 (blocks 0..4095), pool W+bias ----
__global__ void k_prep(const float* __restrict__ x, const float* __restrict__ W,
                       const float* __restrict__ bias,
                       unsigned short* __restrict__ xb, unsigned short* __restrict__ wp,
                       float* __restrict__ biasp) {
  int b = blockIdx.x;
  int t = threadIdx.x;
  if (b < 4096) {
    int i = b * 256 + t;  // 8 elems per thread
    const float4* x4 = (const float4*)x;
    float4 a = x4[i * 2], c = x4[i * 2 + 1];
    uint4 o;
    o.x = f2bf(a.x) | (f2bf(a.y) << 16);
    o.y = f2bf(a.z) | (f2bf(a.w) << 16);
    o.z = f2bf(c.x) | (f2bf(c.y) << 16);
    o.w = f2bf(c.z) | (f2bf(c.w) << 16);
    ((uint4*)xb)[i] = o;
  } else {
    int o = b - 4096;  // pooled feature index
    int r0 = ((o >> 5) << 7) + ((o & 31) << 1);
    const float4* W4 = (const float4*)W;
    float4 w0 = W4[(r0) * 256 + t];
    float4 w1 = W4[(r0 + 1) * 256 + t];
    float4 w2 = W4[(r0 + 64) * 256 + t];
    float4 w3 = W4[(r0 + 65) * 256 + t];
    float ax = 0.25f * (w0.x + w1.x + w2.x + w3.x);
    float ay = 0.25f * (w0.y + w1.y + w2.y + w3.y);
    float az = 0.25f * (w0.z + w1.z + w2.z + w3.z);
    float aw = 0.25f * (w0.w + w1.w + w2.w + w3.w);
    uint2 pk;
    pk.x = f2bf(ax) | (f2bf(ay) << 16);
    pk.y = f2bf(az) | (f2bf(aw) << 16);
    ((uint2*)wp)[o * 256 + t] = pk;
    if (t == 0)
      biasp[o] = 0.25f * (bias[r0] + bias[r0 + 1] + bias[r0 + 64] + bias[r0 + 65]);
  }
}

// ---- kernel 2: GEMM 8192x1024x1024 bf16 MFMA; BM=256 BN=128, 8 waves ----
__global__ __launch_bounds__(512, 2) void k_gemm(
    const unsigned short* __restrict__ xb, const unsigned short* __restrict__ wp,
    const float* __restrict__ biasp, const float* __restrict__ y,
    float* __restrict__ out, float* __restrict__ partials) {
  // buf in {0,1}: As(buf)=smem+buf*49152 (32KB), Bs(buf)=As+32768 (16KB)
  __shared__ char smem[98304];

  int bid = blockIdx.x;
  // XCD swizzle: nwg=256 = 8*32, bijective
  int wg = (bid & 7) * 32 + (bid >> 3);
  int bm0 = (wg >> 3) * BM;   // 32 row tiles
  int bn0 = (wg & 7) * BN;    // 8 col tiles

  int tid = threadIdx.x;
  int lane = tid & 63;
  int wid = tid >> 6;           // 0..7
  int wr = wid >> 1, wc = wid & 1;  // wave tile 64x64: rows wr*64 (0..3), cols wc*64 (0..1)

  f32x4 acc[4][4];
#pragma unroll
  for (int i = 0; i < 4; i++)
#pragma unroll
    for (int j = 0; j < 4; j++) acc[i][j] = (f32x4)0.0f;

  // staging: 512 threads, 16B each -> 64 rows (of 128B) per call.
  // A tile 256 rows = 4 calls; B tile 128 rows = 2 calls. 6 loads/thread/step.
  // LDS dest linear (wave-uniform base + lane*16); SOURCE column chunk
  // pre-swizzled by (lane&7)^(lane>>3) — both-sides involution with the read.
  int srow = tid >> 3;                         // 0..63
  int scol = (((lane & 7) ^ (lane >> 3)) << 3);  // element offset
  const unsigned short* aSrc = xb + (size_t)(bm0 + srow) * KDIM + scol;
  const unsigned short* bSrc = wp + (size_t)(bn0 + srow) * KDIM + scol;
  int ldsOff = wid * 1024;

  // read addressing: fragment row r has r&7 == lane&7; byte col =
  // (kk*64 + (lane>>4)*16) ^ ((lane&7)<<4)
  int rbase = (lane & 15) * 128;
  int xorv = (lane & 7) << 4;
  int cb0 = (((lane >> 4) * 16)) ^ xorv;
  int cb1 = ((64 + (lane >> 4) * 16)) ^ xorv;

#define STAGE(buf, ks)                                                         \
  {                                                                            \
    int k0 = (ks) * BK;                                                        \
    char* ab = smem + (buf) * 49152 + ldsOff;                                  \
    char* bb = smem + (buf) * 49152 + 32768 + ldsOff;                          \
    _Pragma("unroll")                                                          \
    for (int i = 0; i < 4; ++i)                                                \
      gload_lds16(aSrc + (size_t)i * 64 * KDIM + k0, ab + i * 8192);           \
    _Pragma("unroll")                                                          \
    for (int i = 0; i < 2; ++i)                                                \
      gload_lds16(bSrc + (size_t)i * 64 * KDIM + k0, bb + i * 8192);           \
  }

  STAGE(0, 0);
  for (int ks = 0; ks < 16; ++ks) {
    int cur = ks & 1;
    if (ks < 15) {
      STAGE(cur ^ 1, ks + 1);
      asm volatile("s_waitcnt vmcnt(6)" ::: "memory");
    } else {
      asm volatile("s_waitcnt vmcnt(0)" ::: "memory");
    }
    __builtin_amdgcn_s_barrier();
    asm volatile("" ::: "memory");
    const char* Ab = smem + cur * 49152;
    const char* Bb = Ab + 32768;
#pragma unroll
    for (int kk = 0; kk < 2; ++kk) {
      int cb = kk ? cb1 : cb0;
      bf16x8 af[4], bfr[4];
#pragma unroll
      for (int mi = 0; mi < 4; ++mi)
        af[mi] = *(const bf16x8*)(Ab + (wr * 64 + mi * 16) * 128 + rbase + cb);
#pragma unroll
      for (int ni = 0; ni < 4; ++ni)
        bfr[ni] = *(const bf16x8*)(Bb + (wc * 64 + ni * 16) * 128 + rbase + cb);
#pragma unroll
      for (int mi = 0; mi < 4; ++mi)
#pragma unroll
        for (int ni = 0; ni < 4; ++ni)
          acc[mi][ni] = __builtin_amdgcn_mfma_f32_16x16x32_bf16(af[mi], bfr[ni], acc[mi][ni], 0, 0, 0);
    }
    asm volatile("" ::: "memory");
    __builtin_amdgcn_s_barrier();
  }

  // epilogue: add pooled bias + pooled y, write raw out, accumulate block sum
  const float2* y2 = (const float2*)y;
  float tsum = 0.f;
  int r_l = (lane >> 4) * 4;
  int c_l = lane & 15;
#pragma unroll
  for (int mi = 0; mi < 4; ++mi) {
#pragma unroll
    for (int ni = 0; ni < 4; ++ni) {
      int col = bn0 + wc * 64 + ni * 16 + c_l;  // pooled feature o
      float bp = biasp[col];
      int y2base = ((col >> 5) << 6) + (col & 31);
#pragma unroll
      for (int j = 0; j < 4; ++j) {
        int row = bm0 + wr * 64 + mi * 16 + r_l + j;  // batch b
        float2 u = y2[(size_t)row * 2048 + y2base];
        float2 v = y2[(size_t)row * 2048 + y2base + 32];
        float val = acc[mi][ni][j] + bp + 0.25f * (u.x + u.y + v.x + v.y);
        out[(size_t)row * NP + col] = val;
        tsum += val;
      }
    }
  }
#pragma unroll
  for (int off = 32; off > 0; off >>= 1) tsum += __shfl_down(tsum, off);
  float* sm = (float*)smem;
  __syncthreads();
  if (lane == 0) sm[wid] = tsum;
  __syncthreads();
  if (tid == 0)
    partials[bid] = ((sm[0] + sm[1]) + (sm[2] + sm[3])) +
                    ((sm[4] + sm[5]) + (sm[6] + sm[7]));
}

// ---- kernel 3: reduce 256 partials (redundantly per block) + scale out ----
__global__ void k_norm(float* __restrict__ out, const float* __restrict__ partials) {
  __shared__ float s[256];
  int t = threadIdx.x;
  s[t] = partials[t];
  __syncthreads();
#pragma unroll
  for (int off = 128; off > 0; off >>= 1) {
    if (t < off) s[t] += s[t + off];
    __syncthreads();
  }
  float inv = 8388608.0f / s[0];  // (B*NP)/total
  int i = blockIdx.x * 256 + t;
  float4* o4 = (float4*)out;
  float4 v = o4[i];
  v.x *= inv; v.y *= inv; v.z *= inv; v.w *= inv;
  o4[i] = v;
}

extern "C" void kernel_launch(void* const* d_in, const int* in_sizes, int n_in,
                              void* d_out, int out_size, void* d_ws, size_t ws_size,
                              hipStream_t stream) {
  (void)in_sizes; (void)n_in; (void)out_size; (void)ws_size;
  const float* x = (const float*)d_in[0];
  const float* y = (const float*)d_in[1];
  const float* W = (const float*)d_in[2];
  const float* bias = (const float*)d_in[3];
  float* out = (float*)d_out;

  char* ws = (char*)d_ws;
  unsigned short* xb = (unsigned short*)(ws);                 // 16 MiB
  unsigned short* wp = (unsigned short*)(ws + 16777216);      // 2 MiB
  float* biasp = (float*)(ws + 16777216 + 2097152);           // 4 KiB
  float* partials = (float*)(ws + 16777216 + 2097152 + 4096); // 1 KiB

  hipLaunchKernelGGL(k_prep, dim3(5120), dim3(256), 0, stream, x, W, bias, xb, wp, biasp);
  hipLaunchKernelGGL(k_gemm, dim3(NBLK), dim3(512), 0, stream, xb, wp, biasp, y, out, partials);
  hipLaunchKernelGGL(k_norm, dim3(8192), dim3(256), 0, stream, out, partials);
}